// Round 5
// baseline (2140.309 us; speedup 1.0000x reference)
//
#include <hip/hip_runtime.h>
#include <math.h>

// ---------------------------------------------------------------------------
// AdaAttN on MI355X. Attention logits via split-fp16 (hi+lo precomputed in
// memory; 3 MFMAs hh+hl+lh) GEMMs with folded weights M = Wf^T Wg. Value and
// conv GEMMs in fp16 MFMA. f32 for logits, softmax, stats, epilogues.
// R5: occupancy via TN=64 tile variant (128x64, acc 2x4/wave, B staged 16
// rows/wave) on all heavy GEMMs -> grid >=1024 blocks = 4+ blocks/CU with
// ZERO extra HBM traffic / arena growth (unlike more z-splits). R4 z-splits
// retained. Same accumulation order -> bit-identical output.
// ---------------------------------------------------------------------------

typedef _Float16 half8 __attribute__((ext_vector_type(8)));
typedef _Float16 half4 __attribute__((ext_vector_type(4)));
typedef float f32x4 __attribute__((ext_vector_type(4)));

__device__ __forceinline__ void async16(const void* g, void* lds) {
    __builtin_amdgcn_global_load_lds(
        (const __attribute__((address_space(1))) void*)g,
        (__attribute__((address_space(3))) void*)lds, 16, 0, 0);
}

__device__ inline float wave_sum64(float v) {
#pragma unroll
    for (int o = 32; o > 0; o >>= 1) v += __shfl_xor(v, o, 64);
    return v;
}

// ---------------------------------------------------------------------------
// Split-fp16 GEMM: C[m][n] = sum_k A[m][k]*B[n][k], A=Ahi+Alo, B=Bhi+Blo
// (fp16, k-contig, zero-padded). Drops lo*lo. K-split via blockIdx.z ->
// f32 partial plane at Cf + z*splitStride. M mult of 128, N mult of TN,
// K mult of 32. TN=128: 2x2 waves, acc 4x4. TN=64: 4x1 waves, acc 2x4.
// ---------------------------------------------------------------------------
template <int TN>
__global__ __launch_bounds__(256, 2) void mgemm_hl(
    const _Float16* __restrict__ Ahi, const _Float16* __restrict__ Alo,
    const _Float16* __restrict__ Bhi, const _Float16* __restrict__ Blo,
    float* __restrict__ Cf, int K, int lda, int ldb, int ldc,
    size_t splitStride) {
    constexpr int MF = (TN == 128) ? 4 : 2;
    __shared__ _Float16 Ash[4096], Asl[4096], Bsh[TN * 32], Bsl[TN * 32];
    const int t = threadIdx.x, wave = t >> 6, lane = t & 63;
    const int bm = blockIdx.y * 128, bn = blockIdx.x * TN;
    const int kbase = blockIdx.z * K;
    const int wr = (TN == 128) ? (wave >> 1) * 64 : wave * 32;
    const int wc = (TN == 128) ? (wave & 1) * 64 : 0;
    const int lq = lane >> 4, lr = lane & 15;
    const int srow = wave * 32 + (lane >> 2);
    const int srowB = (TN == 128) ? srow : wave * 16 + (lane >> 2);
    const int scolg = (lane & 3) ^ ((lane >> 3) & 3);

    f32x4 acc[MF][4] = {};

    const size_t aoff = ((size_t)(bm + srow) * lda + kbase) * 2 + scolg * 16;
    const size_t boff = ((size_t)(bn + srowB) * ldb + kbase) * 2 + scolg * 16;
    const char* pAh = (const char*)Ahi + aoff;
    const char* pAl = (const char*)Alo + aoff;
    const char* pBh = (const char*)Bhi + boff;
    const char* pBl = (const char*)Blo + boff;
    const size_t ar = (size_t)16 * lda * 2, br = (size_t)16 * ldb * 2;
    _Float16* dAh = Ash + wave * 1024;
    _Float16* dAl = Asl + wave * 1024;
    _Float16* dBh = (TN == 128) ? Bsh + wave * 1024 : Bsh + wave * 512;
    _Float16* dBl = (TN == 128) ? Bsl + wave * 1024 : Bsl + wave * 512;
    const int key = (lr >> 1) & 3;

    for (int k0 = 0; k0 < K; k0 += 32) {
        __syncthreads();
        async16(pAh, dAh);
        async16(pAh + ar, dAh + 512);
        async16(pAl, dAl);
        async16(pAl + ar, dAl + 512);
        async16(pBh, dBh);
        async16(pBl, dBl);
        if (TN == 128) {
            async16(pBh + br, dBh + 512);
            async16(pBl + br, dBl + 512);
        }
        pAh += 64;
        pAl += 64;
        pBh += 64;
        pBl += 64;
        __syncthreads();

        half8 ah[MF], al[MF], bh[4], bl[4];
#pragma unroll
        for (int i = 0; i < MF; i++) {
            const int ro = (wr + i * 16 + lr) * 32 + ((lq ^ key) * 8);
            ah[i] = *(const half8*)&Ash[ro];
            al[i] = *(const half8*)&Asl[ro];
        }
#pragma unroll
        for (int j = 0; j < 4; j++) {
            const int ro = (wc + j * 16 + lr) * 32 + ((lq ^ key) * 8);
            bh[j] = *(const half8*)&Bsh[ro];
            bl[j] = *(const half8*)&Bsl[ro];
        }
#pragma unroll
        for (int i = 0; i < MF; i++)
#pragma unroll
            for (int j = 0; j < 4; j++) {
                acc[i][j] = __builtin_amdgcn_mfma_f32_16x16x32_f16(
                    ah[i], bl[j], acc[i][j], 0, 0, 0);
                acc[i][j] = __builtin_amdgcn_mfma_f32_16x16x32_f16(
                    al[i], bh[j], acc[i][j], 0, 0, 0);
                acc[i][j] = __builtin_amdgcn_mfma_f32_16x16x32_f16(
                    ah[i], bh[j], acc[i][j], 0, 0, 0);
            }
    }
    float* Co = Cf + (size_t)blockIdx.z * splitStride;
#pragma unroll
    for (int i = 0; i < MF; i++) {
        const int m0 = bm + wr + i * 16 + lq * 4;
#pragma unroll
        for (int j = 0; j < 4; j++) {
            const int n = bn + wc + j * 16 + lr;
#pragma unroll
            for (int r = 0; r < 4; r++)
                Co[(size_t)(m0 + r) * ldc + n] = acc[i][j][r];
        }
    }
}

// ---------------------------------------------------------------------------
// fp16 GEMM: C[m][n] = sum_k A[m][k]*B[n][k] (+bias). A,B fp16 k-contig.
// BIAS_MODE: 0 none, 2 bias[m]. OUT_MODE: 0 f32->Cf(+z*splitStride),
// 2 fp16 dual rows (v at m, v*v at m+512). CONV: B = pad4T[py][px][ci].
// TN as in mgemm_hl.
// ---------------------------------------------------------------------------
template <int BIAS_MODE, int OUT_MODE, bool CONV, int TN>
__global__ __launch_bounds__(256, 2) void mgemm16(
    const _Float16* __restrict__ A, const _Float16* __restrict__ B,
    const float* __restrict__ bias, float* __restrict__ Cf,
    _Float16* __restrict__ Ch, int K, int lda, int ldb, int ldc,
    size_t splitStride) {
    constexpr int MF = (TN == 128) ? 4 : 2;
    __shared__ _Float16 As[128 * 32];
    __shared__ _Float16 Bs[TN * 32];
    const int t = threadIdx.x, wave = t >> 6, lane = t & 63;
    const int bm = blockIdx.y * 128, bn = blockIdx.x * TN;
    const int kbase = blockIdx.z * K;
    const int wr = (TN == 128) ? (wave >> 1) * 64 : wave * 32;
    const int wc = (TN == 128) ? (wave & 1) * 64 : 0;
    const int lq = lane >> 4, lr = lane & 15;
    const int srow = wave * 32 + (lane >> 2);
    const int srowB = (TN == 128) ? srow : wave * 16 + (lane >> 2);
    const int scolg = (lane & 3) ^ ((lane >> 3) & 3);

    f32x4 acc[MF][4] = {};

    const char* Ap = (const char*)A +
                     ((size_t)(bm + srow) * lda + kbase) * 2 + scolg * 16;
    const char* Bp = (const char*)B +
                     ((size_t)(bn + srowB) * ldb + kbase) * 2 + scolg * 16;
    const size_t Astep = (size_t)16 * lda * 2;
    const size_t Bstep = (size_t)16 * ldb * 2;
    _Float16* As0 = &As[(wave * 32) * 32];
    _Float16* As1 = &As[(wave * 32 + 16) * 32];
    _Float16* Bs0 = (TN == 128) ? &Bs[(wave * 32) * 32] : &Bs[(wave * 16) * 32];
    _Float16* Bs1 = (TN == 128) ? &Bs[(wave * 32 + 16) * 32] : nullptr;
    const int key = (lr >> 1) & 3;

    for (int k0 = 0; k0 < K; k0 += 32) {
        __syncthreads();
        async16(Ap, As0);
        async16(Ap + Astep, As1);
        if (CONV) {
            const int kg = kbase + k0;
            const int rI = kg >> 9;
            const int dy = rI / 3, dx = rI - 3 * dy;
            const int ci0 = kg & 511;
            const int py = (bn >> 7) + dy;
            const int px = (bn & 127) + srowB + dx;
            const char* Bc = (const char*)B +
                             (((size_t)py * 130 + px) * 512 + ci0) * 2 +
                             scolg * 16;
            async16(Bc, Bs0);
            if (TN == 128) async16(Bc + (size_t)16 * 512 * 2, Bs1);
        } else {
            async16(Bp, Bs0);
            if (TN == 128) async16(Bp + Bstep, Bs1);
            Bp += 64;
        }
        Ap += 64;
        __syncthreads();

        half8 af[MF], bf[4];
#pragma unroll
        for (int i = 0; i < MF; i++)
            af[i] = *(const half8*)&As[(wr + i * 16 + lr) * 32 + (lq ^ key) * 8];
#pragma unroll
        for (int j = 0; j < 4; j++)
            bf[j] = *(const half8*)&Bs[(wc + j * 16 + lr) * 32 + (lq ^ key) * 8];
#pragma unroll
        for (int i = 0; i < MF; i++)
#pragma unroll
            for (int j = 0; j < 4; j++)
                acc[i][j] = __builtin_amdgcn_mfma_f32_16x16x32_f16(
                    af[i], bf[j], acc[i][j], 0, 0, 0);
    }

    float* Co = (OUT_MODE == 0) ? Cf + (size_t)blockIdx.z * splitStride : nullptr;
#pragma unroll
    for (int i = 0; i < MF; i++) {
        const int m0 = bm + wr + i * 16 + lq * 4;
#pragma unroll
        for (int j = 0; j < 4; j++) {
            const int n = bn + wc + j * 16 + lr;
#pragma unroll
            for (int r = 0; r < 4; r++) {
                const int m = m0 + r;
                float v = acc[i][j][r];
                if (BIAS_MODE == 2) v += bias[m];
                if (OUT_MODE == 0) {
                    Co[(size_t)m * ldc + n] = v;
                } else {
                    Ch[(size_t)m * ldc + n] = (_Float16)v;
                    Ch[(size_t)(m + 512) * ldc + n] = (_Float16)(v * v);
                }
            }
        }
    }
}

// ---------------------------------------------------------------------------
// combine z-partials -> hi/lo fp16 pair. count multiple of 256.
__global__ __launch_bounds__(256) void combine_hilo(
    const float* __restrict__ part, _Float16* __restrict__ hi,
    _Float16* __restrict__ lo, int nz, size_t zs) {
    size_t i = (size_t)blockIdx.x * 256 + threadIdx.x;
    float s = 0.f;
    for (int z = 0; z < nz; z++) s += part[z * zs + i];
    _Float16 h = (_Float16)s;
    hi[i] = h;
    lo[i] = (_Float16)(s - (float)h);
}

// ---------------------------------------------------------------------------
// transpose f32 -> hi/lo fp16 pair: dsthi/lo[n][c] from src[c][n], zero-fill
// outside (cvalid, nvalid). grid (Npad/32, Cpad/32).
__global__ __launch_bounds__(256) void transpose_hilo(
    const float* __restrict__ src, _Float16* __restrict__ dsthi,
    _Float16* __restrict__ dstlo, long srcld, int dstld, int nvalid,
    int cvalid) {
    __shared__ float tile[32][33];
    const int t = threadIdx.x, tx = t & 31, ty = t >> 5;
    const int n0 = blockIdx.x * 32, c0 = blockIdx.y * 32;
    const int n = n0 + tx;
#pragma unroll
    for (int i = 0; i < 4; i++) {
        int c = c0 + ty + i * 8;
        tile[ty + i * 8][tx] =
            (c < cvalid && n < nvalid) ? src[(size_t)c * srcld + n] : 0.f;
    }
    __syncthreads();
#pragma unroll
    for (int i = 0; i < 4; i++) {
        int nn = ty + i * 8;
        float v = tile[tx][nn];
        _Float16 h = (_Float16)v;
        size_t o = (size_t)(n0 + nn) * dstld + c0 + tx;
        dsthi[o] = h;
        dstlo[o] = (_Float16)(v - (float)h);
    }
}

// transpose f32->fp16 (full-valid). src [C][srcld], dst fp16 [N][dstld].
__global__ __launch_bounds__(256) void transpose_cvt16(
    const float* __restrict__ src, _Float16* __restrict__ dst, long srcld,
    int dstld) {
    __shared__ float tile[32][33];
    const int t = threadIdx.x, tx = t & 31, ty = t >> 5;
    const int n0 = blockIdx.x * 32, c0 = blockIdx.y * 32;
#pragma unroll
    for (int i = 0; i < 4; i++)
        tile[ty + i * 8][tx] = src[(size_t)(c0 + ty + i * 8) * srcld + n0 + tx];
    __syncthreads();
#pragma unroll
    for (int i = 0; i < 4; i++) {
        int nn = ty + i * 8;
        dst[(size_t)(n0 + nn) * dstld + c0 + tx] = (_Float16)tile[tx][nn];
    }
}

// elementwise f32 -> fp16
__global__ __launch_bounds__(256) void cvt16(const float* __restrict__ src,
                                             _Float16* __restrict__ dst) {
    int i = blockIdx.x * 256 + threadIdx.x;
    dst[i] = (_Float16)src[i];
}

// conv weight permute: [o][ci][3][3] f32 -> [o][(dy*3+dx)*512+ci] fp16
__global__ __launch_bounds__(256) void convw_perm(const float* __restrict__ src,
                                                  _Float16* __restrict__ dst) {
    int idx = blockIdx.x * 256 + threadIdx.x;
    int o = idx / 4608, rem = idx - o * 4608;
    int r = rem >> 9, ci = rem & 511;
    dst[idx] = (_Float16)src[(size_t)o * 4608 + ci * 9 + r];
}

// out[n] = (addc ? addc[0] : 0) + sum_c vec[c] * mat[c*ldm + n]
__global__ __launch_bounds__(256) void fold_vec(
    const float* __restrict__ mat, const float* __restrict__ vec,
    const float* __restrict__ addc, float* __restrict__ outv, int C, int Nout,
    long ldm) {
    __shared__ float red[4][64];
    const int t = threadIdx.x, lane = t & 63, seg = t >> 6;
    const int n = blockIdx.x * 64 + lane;
    const int chunk = (C + 3) >> 2;
    const int start = seg * chunk;
    const int end = min(C, start + chunk);
    float s0 = 0.f, s1 = 0.f, s2 = 0.f, s3 = 0.f;
    if (n < Nout) {
        int c = start;
        for (; c + 3 < end; c += 4) {
            s0 = fmaf(vec[c], mat[(size_t)c * ldm + n], s0);
            s1 = fmaf(vec[c + 1], mat[(size_t)(c + 1) * ldm + n], s1);
            s2 = fmaf(vec[c + 2], mat[(size_t)(c + 2) * ldm + n], s2);
            s3 = fmaf(vec[c + 3], mat[(size_t)(c + 3) * ldm + n], s3);
        }
        for (; c < end; c++) s0 = fmaf(vec[c], mat[(size_t)c * ldm + n], s0);
    }
    red[seg][lane] = (s0 + s1) + (s2 + s3);
    __syncthreads();
    if (seg == 0 && n < Nout)
        outv[n] = red[0][lane] + red[1][lane] + red[2][lane] + red[3][lane] +
                  (addc ? addc[0] : 0.f);
}

// out[0] = dot(a, b) over C. One block.
__global__ __launch_bounds__(256) void dotbb(const float* __restrict__ a,
                                             const float* __restrict__ b,
                                             float* __restrict__ out, int C) {
    __shared__ float red[4];
    const int t = threadIdx.x;
    float s = 0.f;
    for (int c = t; c < C; c += 256) s = fmaf(a[c], b[c], s);
    s = wave_sum64(s);
    if ((t & 63) == 0) red[t >> 6] = s;
    __syncthreads();
    if (t == 0) out[0] = red[0] + red[1] + red[2] + red[3];
}

// Softmax: sums NZ logit planes (zs float stride) + rr, row in registers,
// single exp pass, fp16 out. cols = NPER*256.
template <int NPER, int NZ>
__global__ __launch_bounds__(256) void softmax2(const float* __restrict__ L,
                                                const float* __restrict__ rr,
                                                _Float16* __restrict__ S,
                                                size_t zs) {
    constexpr int NV = NPER / 4;
    __shared__ float redm[4], reds[4];
    const int t = threadIdx.x;
    const float* p = L + (size_t)blockIdx.x * (NPER * 256);
    _Float16* q = S + (size_t)blockIdx.x * (NPER * 256);
    f32x4 v[NV];
    float m = -3.0e38f;
#pragma unroll
    for (int i = 0; i < NV; i++) {
        const int c = t * 4 + i * 1024;
        f32x4 x = *(const f32x4*)(p + c);
        if (NZ == 2) x = x + *(const f32x4*)(p + zs + c);
        x = x + *(const f32x4*)(rr + c);
        v[i] = x;
        m = fmaxf(m, fmaxf(fmaxf(x[0], x[1]), fmaxf(x[2], x[3])));
    }
#pragma unroll
    for (int o = 32; o > 0; o >>= 1) m = fmaxf(m, __shfl_xor(m, o, 64));
    if ((t & 63) == 0) redm[t >> 6] = m;
    __syncthreads();
    m = fmaxf(fmaxf(redm[0], redm[1]), fmaxf(redm[2], redm[3]));
    float s = 0.f;
#pragma unroll
    for (int i = 0; i < NV; i++) {
        f32x4 x = v[i];
#pragma unroll
        for (int j = 0; j < 4; j++) {
            x[j] = __expf(x[j] - m);
            s += x[j];
        }
        v[i] = x;
    }
    s = wave_sum64(s);
    if ((t & 63) == 0) reds[t >> 6] = s;
    __syncthreads();
    const float inv = 1.f / (reds[0] + reds[1] + reds[2] + reds[3]);
#pragma unroll
    for (int i = 0; i < NV; i++) {
        const int c = t * 4 + i * 1024;
        half4 h;
#pragma unroll
        for (int j = 0; j < 4; j++) h[j] = (_Float16)(v[i][j] * inv);
        *(half4*)(q + c) = h;
    }
}

// Per-channel mean & unbiased std (+1e-6). One block per channel.
__global__ __launch_bounds__(256) void chanstats_kernel(
    const float* __restrict__ x, float* __restrict__ cm,
    float* __restrict__ cstd, int N) {
    __shared__ float rs[4], rs2[4];
    const int t = threadIdx.x;
    const float* p = x + (size_t)blockIdx.x * N;
    float s = 0.f, s2 = 0.f;
    for (int i = t; i < N; i += 256) {
        float v = p[i];
        s += v;
        s2 = fmaf(v, v, s2);
    }
    s = wave_sum64(s);
    s2 = wave_sum64(s2);
    if ((t & 63) == 0) {
        rs[t >> 6] = s;
        rs2[t >> 6] = s2;
    }
    __syncthreads();
    if (t == 0) {
        float S = rs[0] + rs[1] + rs[2] + rs[3];
        float S2 = rs2[0] + rs2[1] + rs2[2] + rs2[3];
        float mean = S / N;
        float var = fmaxf((S2 - S * mean) / (N - 1), 0.f);
        cm[blockIdx.x] = mean;
        cstd[blockIdx.x] = sqrtf(var) + 1e-6f;
    }
}

// a5T[n][c] fp16 = std*instnorm(content5) + mean; pv = 2 z-planes [4096][1024]
__global__ __launch_bounds__(256) void epilogue5(
    const float* __restrict__ pv, const float* __restrict__ content,
    const float* __restrict__ cm, const float* __restrict__ cstd,
    _Float16* __restrict__ a5t) {
    int idx = blockIdx.x * 256 + threadIdx.x;  // n*512 + c
    int n = idx >> 9, c = idx & 511;
    const size_t SS = (size_t)4096 * 1024;
    float mean = pv[(size_t)n * 1024 + c] + pv[SS + (size_t)n * 1024 + c];
    float ex2 =
        pv[(size_t)n * 1024 + 512 + c] + pv[SS + (size_t)n * 1024 + 512 + c];
    float sd = sqrtf(fmaxf(ex2 - mean * mean, 0.f));
    float cn = (content[(size_t)c * 4096 + n] - cm[c]) / cstd[c];
    a5t[idx] = (_Float16)(fmaf(sd, cn, mean));
}

// pad4T interior <- a4 + upsample2(a5), one 1024-pixel chunk, 8 K-splits.
__global__ __launch_bounds__(256) void epilogue4(
    const float* __restrict__ part, const float* __restrict__ content,
    const float* __restrict__ cm, const float* __restrict__ cstd,
    const _Float16* __restrict__ a5t, _Float16* __restrict__ pad4t, int n0) {
    int idx = blockIdx.x * 256 + threadIdx.x;  // r*512 + c
    int r = idx >> 9, c = idx & 511;
    int n = n0 + r;
    const size_t SS = (size_t)1024 * 1024;
    float mean = 0.f, ex2 = 0.f;
#pragma unroll
    for (int z = 0; z < 8; z++) {
        mean += part[z * SS + (size_t)r * 1024 + c];
        ex2 += part[z * SS + (size_t)r * 1024 + 512 + c];
    }
    float sd = sqrtf(fmaxf(ex2 - mean * mean, 0.f));
    float cn = (content[(size_t)c * 16384 + n] - cm[c]) / cstd[c];
    int y = n >> 7, x = n & 127;
    float up = (float)a5t[(size_t)((y >> 1) * 64 + (x >> 1)) * 512 + c];
    pad4t[(size_t)((y + 1) * 130 + (x + 1)) * 512 + c] =
        (_Float16)(fmaf(sd, cn, mean) + up);
}

__global__ __launch_bounds__(256) void border_kernel(_Float16* __restrict__ pad) {
    int idx = blockIdx.x * 256 + threadIdx.x;  // pos*512 + c
    int pos = idx >> 9, c = idx & 511;
    int py, px;
    if (pos < 130) { py = 0; px = pos; }
    else if (pos < 260) { py = 129; px = pos - 130; }
    else if (pos < 388) { py = pos - 260 + 1; px = 0; }
    else { py = pos - 388 + 1; px = 129; }
    int sy = py == 0 ? 2 : (py == 129 ? 127 : py);
    int sx = px == 0 ? 2 : (px == 129 ? 127 : px);
    pad[(size_t)(py * 130 + px) * 512 + c] =
        pad[(size_t)(sy * 130 + sx) * 512 + c];
}

// ---------------------------------------------------------------------------

extern "C" void kernel_launch(void* const* d_in, const int* in_sizes, int n_in,
                              void* d_out, int out_size, void* d_ws,
                              size_t ws_size, hipStream_t stream) {
    (void)in_sizes; (void)n_in; (void)out_size; (void)ws_size;
    const float* content4 = (const float*)d_in[0];
    const float* style4 = (const float*)d_in[1];
    const float* content5 = (const float*)d_in[2];
    const float* style5 = (const float*)d_in[3];
    const float* ckey4 = (const float*)d_in[4];
    const float* skey4 = (const float*)d_in[5];
    const float* ckey5 = (const float*)d_in[6];
    const float* skey5 = (const float*)d_in[7];
    const float* f4w = (const float*)d_in[8];
    const float* f4b = (const float*)d_in[9];
    const float* g4w = (const float*)d_in[10];
    const float* g4b = (const float*)d_in[11];
    const float* h4w = (const float*)d_in[12];
    const float* h4b = (const float*)d_in[13];
    const float* f5w = (const float*)d_in[14];
    const float* f5b = (const float*)d_in[15];
    const float* g5w = (const float*)d_in[16];
    const float* g5b = (const float*)d_in[17];
    const float* h5w = (const float*)d_in[18];
    const float* h5b = (const float*)d_in[19];
    const float* convw = (const float*)d_in[20];
    const float* convb = (const float*)d_in[21];
    float* out = (float*)d_out;
    char* ws = (char*)d_ws;

    // ---- persistent regions (byte offsets) ----
    _Float16* PAD4T = (_Float16*)(ws + 0);         // [130][130][512]
    _Float16* A5T = (_Float16*)(ws + 17305600);    // [4096][512]
    float* STATS = (float*)(ws + 21499904);        // 2048 f32
    _Float16* H4W = (_Float16*)(ws + 21508096);    // [512][512]
    _Float16* H5W = (_Float16*)(ws + 22032384);
    _Float16* CONVW = (_Float16*)(ws + 22556672);  // [512][4608]
    float* U5 = (float*)(ws + 27275264);           // 1472
    float* R5 = (float*)(ws + 27283456);           // 1024
    float* U4 = (float*)(ws + 27291648);           // 960
    float* R4 = (float*)(ws + 27299840);           // 4096
    float* BB5 = (float*)(ws + 27316224);
    float* BB4 = (float*)(ws + 27316480);
    char* A0 = ws + 27320320;  // arena

    float* cm4 = STATS, *cstd4 = STATS + 512, *cm5 = STATS + 1024,
         *cstd5 = STATS + 1536;

    chanstats_kernel<<<512, 256, 0, stream>>>(content5, cm5, cstd5, 4096);
    chanstats_kernel<<<512, 256, 0, stream>>>(content4, cm4, cstd4, 16384);
    cvt16<<<1024, 256, 0, stream>>>(h4w, H4W);
    cvt16<<<1024, 256, 0, stream>>>(h5w, H5W);
    convw_perm<<<9216, 256, 0, stream>>>(convw, CONVW);

    // ================= Layer 5 (Nc=4096, Ns=1024, Ck=1472->1536) ===========
    {
        _Float16* STT5 = (_Float16*)(A0 + 0);         // [1024][512]
        _Float16* HCAT5 = (_Float16*)(A0 + 1048576);  // [1024][1024]
        _Float16* T5h = (_Float16*)(A0 + 3145728);    // [1024][1536]
        _Float16* T5l = (_Float16*)(A0 + 6291456);
        _Float16* FWh = (_Float16*)(A0 + 9437184);    // [1536][1536]
        _Float16* FWl = (_Float16*)(A0 + 14155776);
        _Float16* GWh = (_Float16*)(A0 + 18874368);
        _Float16* GWl = (_Float16*)(A0 + 23592960);
        float* PM5 = (float*)(A0 + 28311552);         // 3x[1536][1536] f32
        _Float16* M5h = (_Float16*)(A0 + 56623104);   // [1536][1536]
        _Float16* M5l = (_Float16*)(A0 + 61341696);
        _Float16* SKh = (_Float16*)(A0 + 9437184);    // [1024][1536] (post-PM5)
        _Float16* SKl = (_Float16*)(A0 + 12582912);
        float* PT5 = (float*)(A0 + 15728640);         // 3x[1024][1536] f32
        _Float16* CKh = (_Float16*)(A0 + 9437184);    // [4096][1536] (post-T5)
        _Float16* CKl = (_Float16*)(A0 + 22020096);
        float* LOG5 = (float*)(A0 + 34603008);        // 2x[4096][1024] f32
        _Float16* S5 = (_Float16*)(A0 + 9437184);     // [4096][1024] (post-log)

        dotbb<<<1, 256, 0, stream>>>(f5b, g5b, BB5, 1472);
        fold_vec<<<23, 256, 0, stream>>>(g5w, f5b, nullptr, U5, 1472, 1472, 1472);
        fold_vec<<<16, 256, 0, stream>>>(skey5, U5, BB5, R5, 1472, 1024, 1024);

        transpose_hilo<<<dim3(48, 48), 256, 0, stream>>>(f5w, FWh, FWl, 1472,
                                                         1536, 1472, 1472);
        transpose_hilo<<<dim3(48, 48), 256, 0, stream>>>(g5w, GWh, GWl, 1472,
                                                         1536, 1472, 1472);
        // M5 = FW x GW, K=1536 split z=3, TN=64
        mgemm_hl<64><<<dim3(24, 12, 3), 256, 0, stream>>>(
            FWh, FWl, GWh, GWl, PM5, 512, 1536, 1536, 1536,
            (size_t)1536 * 1536);
        combine_hilo<<<9216, 256, 0, stream>>>(PM5, M5h, M5l, 3,
                                               (size_t)1536 * 1536);
        transpose_hilo<<<dim3(32, 48), 256, 0, stream>>>(skey5, SKh, SKl, 1024,
                                                         1536, 1024, 1472);
        // T5 = SK x M5, K=1536 split z=3, TN=64
        mgemm_hl<64><<<dim3(24, 8, 3), 256, 0, stream>>>(
            SKh, SKl, M5h, M5l, PT5, 512, 1536, 1536, 1536,
            (size_t)1024 * 1536);
        combine_hilo<<<6144, 256, 0, stream>>>(PT5, T5h, T5l, 3,
                                               (size_t)1024 * 1536);
        transpose_cvt16<<<dim3(32, 16), 256, 0, stream>>>(style5, STT5, 1024, 512);
        mgemm16<2, 2, false, 128><<<dim3(8, 4), 256, 0, stream>>>(
            H5W, STT5, h5b, nullptr, HCAT5, 512, 512, 512, 1024, 0);
        transpose_hilo<<<dim3(128, 48), 256, 0, stream>>>(ckey5, CKh, CKl, 4096,
                                                          1536, 4096, 1472);
        // logits = CK x T5, K=1536 split z=2 -> 2 planes, TN=64
        mgemm_hl<64><<<dim3(16, 32, 2), 256, 0, stream>>>(
            CKh, CKl, T5h, T5l, LOG5, 768, 1536, 1536, 1024,
            (size_t)4096 * 1024);
        softmax2<4, 2><<<4096, 256, 0, stream>>>(LOG5, R5, S5,
                                                 (size_t)4096 * 1024);
        // PV, K=1024 split z=2 -> 2 planes into LOG5 region, TN=64
        mgemm16<0, 0, false, 64><<<dim3(16, 32, 2), 256, 0, stream>>>(
            S5, HCAT5, nullptr, LOG5, nullptr, 512, 1024, 1024, 1024,
            (size_t)4096 * 1024);
        epilogue5<<<8192, 256, 0, stream>>>(LOG5, content5, cm5, cstd5, A5T);
    }

    // ================= Layer 4 (Nc=16384, Ns=4096, Ck=960->1024) ===========
    {
        _Float16* T4h = (_Float16*)(A0 + 0);          // [4096][1024]
        _Float16* T4l = (_Float16*)(A0 + 8388608);
        _Float16* M4h = (_Float16*)(A0 + 16777216);   // [1024][1024]
        _Float16* M4l = (_Float16*)(A0 + 18874368);
        _Float16* FWh = (_Float16*)(A0 + 20971520);   // [1024][1024]
        _Float16* FWl = (_Float16*)(A0 + 23068672);
        _Float16* GWh = (_Float16*)(A0 + 25165824);
        _Float16* GWl = (_Float16*)(A0 + 27262976);
        float* PM4 = (float*)(A0 + 29360128);         // 4x[1024][1024] f32
        _Float16* SKh = (_Float16*)(A0 + 20971520);   // [4096][1024] (post-PM4)
        _Float16* SKl = (_Float16*)(A0 + 29360128);
        float* PT4 = (float*)(A0 + 37748736);         // 2x[4096][1024] f32
        _Float16* HCAT4 = (_Float16*)(A0 + 16777216); // [1024][4096] (post-T4)
        _Float16* STT4 = (_Float16*)(A0 + 25165824);  // [4096][512]
        _Float16* CKh = (_Float16*)(A0 + 29360128);   // [1024][1024] per chunk
        _Float16* CKl = (_Float16*)(A0 + 31457280);
        _Float16* S4 = (_Float16*)(A0 + 25165824);    // [1024][4096] (in loop)
        float* LOGR = (float*)(A0 + 33554432);        // 2x[1024][4096] f32/PART

        dotbb<<<1, 256, 0, stream>>>(f4b, g4b, BB4, 960);
        fold_vec<<<15, 256, 0, stream>>>(g4w, f4b, nullptr, U4, 960, 960, 960);
        fold_vec<<<64, 256, 0, stream>>>(skey4, U4, BB4, R4, 960, 4096, 4096);

        transpose_hilo<<<dim3(32, 32), 256, 0, stream>>>(f4w, FWh, FWl, 960,
                                                         1024, 960, 960);
        transpose_hilo<<<dim3(32, 32), 256, 0, stream>>>(g4w, GWh, GWl, 960,
                                                         1024, 960, 960);
        // M4 = FW x GW, K=1024 split z=4, TN=64
        mgemm_hl<64><<<dim3(16, 8, 4), 256, 0, stream>>>(
            FWh, FWl, GWh, GWl, PM4, 256, 1024, 1024, 1024,
            (size_t)1024 * 1024);
        combine_hilo<<<4096, 256, 0, stream>>>(PM4, M4h, M4l, 4,
                                               (size_t)1024 * 1024);
        transpose_hilo<<<dim3(128, 32), 256, 0, stream>>>(skey4, SKh, SKl, 4096,
                                                          1024, 4096, 960);
        // T4 = SK x M4, K=1024 split z=2, TN=64
        mgemm_hl<64><<<dim3(16, 32, 2), 256, 0, stream>>>(
            SKh, SKl, M4h, M4l, PT4, 512, 1024, 1024, 1024,
            (size_t)4096 * 1024);
        combine_hilo<<<16384, 256, 0, stream>>>(PT4, T4h, T4l, 2,
                                                (size_t)4096 * 1024);
        transpose_cvt16<<<dim3(128, 16), 256, 0, stream>>>(style4, STT4, 4096, 512);
        mgemm16<2, 2, false, 128><<<dim3(32, 4), 256, 0, stream>>>(
            H4W, STT4, h4b, nullptr, HCAT4, 512, 512, 512, 4096, 0);

        for (int chunk = 0; chunk < 16; chunk++) {
            const int n0 = chunk * 1024;
            transpose_hilo<<<dim3(32, 32), 256, 0, stream>>>(
                ckey4 + n0, CKh, CKl, 16384, 1024, 1024, 960);
            // logits = CK x T4, K=1024 split z=2 -> 2 planes, TN=64
            mgemm_hl<64><<<dim3(64, 8, 2), 256, 0, stream>>>(
                CKh, CKl, T4h, T4l, LOGR, 512, 1024, 1024, 4096,
                (size_t)1024 * 4096);
            softmax2<16, 2><<<1024, 256, 0, stream>>>(LOGR, R4, S4,
                                                      (size_t)1024 * 4096);
            // PV, K=4096 split z=8 -> 8 planes into LOGR region, TN=64
            mgemm16<0, 0, false, 64><<<dim3(16, 8, 8), 256, 0, stream>>>(
                S4, HCAT4, nullptr, LOGR, nullptr, 512, 4096, 4096, 1024,
                (size_t)1024 * 1024);
            epilogue4<<<2048, 256, 0, stream>>>(LOGR, content4, cm4, cstd4, A5T,
                                                PAD4T, n0);
        }
    }

    border_kernel<<<1032, 256, 0, stream>>>(PAD4T);
    mgemm16<2, 0, true, 64><<<dim3(256, 4), 256, 0, stream>>>(
        CONVW, PAD4T, convb, out, nullptr, 4608, 4608, 512, 16384, 0);
}

// Round 6
// 1963.516 us; speedup vs baseline: 1.0900x; 1.0900x over previous
//
#include <hip/hip_runtime.h>
#include <math.h>

// ---------------------------------------------------------------------------
// AdaAttN on MI355X. Attention logits via split-fp16 (hi+lo precomputed in
// memory; 3 MFMAs hh+hl+lh) GEMMs with folded weights M = Wf^T Wg. Value and
// conv GEMMs in fp16 MFMA. f32 for logits, softmax, stats, epilogues.
// R6: revert R5's TN=64 (LDS-intensity loss); keep R4 z-splits/grids (1993us).
// + BK=64: two 32-K sub-tiles per barrier pair -> halves barrier/drain events.
// + phase-desync: co-resident blocks (linear id +-256) offset by s_sleep so
//   one block computes while the other drains (anti-lockstep).
// Same K accumulation order -> bit-identical output vs R4.
// ---------------------------------------------------------------------------

typedef _Float16 half8 __attribute__((ext_vector_type(8)));
typedef _Float16 half4 __attribute__((ext_vector_type(4)));
typedef float f32x4 __attribute__((ext_vector_type(4)));

__device__ __forceinline__ void async16(const void* g, void* lds) {
    __builtin_amdgcn_global_load_lds(
        (const __attribute__((address_space(1))) void*)g,
        (__attribute__((address_space(3))) void*)lds, 16, 0, 0);
}

__device__ __forceinline__ void desync_sleep() {
    const int lin =
        blockIdx.x + gridDim.x * (blockIdx.y + gridDim.y * blockIdx.z);
    if ((lin >> 8) & 1) __builtin_amdgcn_s_sleep(7);
}

__device__ inline float wave_sum64(float v) {
#pragma unroll
    for (int o = 32; o > 0; o >>= 1) v += __shfl_xor(v, o, 64);
    return v;
}

// ---------------------------------------------------------------------------
// Split-fp16 GEMM: C[m][n] = sum_k A[m][k]*B[n][k], A=Ahi+Alo, B=Bhi+Blo
// (fp16, k-contig, zero-padded). Drops lo*lo. K-split via blockIdx.z ->
// f32 partial plane at Cf + z*splitStride. M,N mult of 128, K mult of 64.
// BK=64: two 32-K sub-tiles staged per barrier pair.
// ---------------------------------------------------------------------------
__global__ __launch_bounds__(256, 2) void mgemm_hl(
    const _Float16* __restrict__ Ahi, const _Float16* __restrict__ Alo,
    const _Float16* __restrict__ Bhi, const _Float16* __restrict__ Blo,
    float* __restrict__ Cf, int K, int lda, int ldb, int ldc,
    size_t splitStride) {
    __shared__ _Float16 Ash[8192], Asl[8192], Bsh[8192], Bsl[8192];
    const int t = threadIdx.x, wave = t >> 6, lane = t & 63;
    const int bm = blockIdx.y * 128, bn = blockIdx.x * 128;
    const int kbase = blockIdx.z * K;
    const int wr = (wave >> 1) * 64, wc = (wave & 1) * 64;
    const int lq = lane >> 4, lr = lane & 15;
    const int srow = wave * 32 + (lane >> 2);
    const int scolg = (lane & 3) ^ ((lane >> 3) & 3);

    desync_sleep();

    f32x4 acc[4][4] = {};

    const size_t aoff = ((size_t)(bm + srow) * lda + kbase) * 2 + scolg * 16;
    const size_t boff = ((size_t)(bn + srow) * ldb + kbase) * 2 + scolg * 16;
    const char* pAh = (const char*)Ahi + aoff;
    const char* pAl = (const char*)Alo + aoff;
    const char* pBh = (const char*)Bhi + boff;
    const char* pBl = (const char*)Blo + boff;
    const size_t ar = (size_t)16 * lda * 2, br = (size_t)16 * ldb * 2;
    _Float16* dAh = Ash + wave * 1024;
    _Float16* dAl = Asl + wave * 1024;
    _Float16* dBh = Bsh + wave * 1024;
    _Float16* dBl = Bsl + wave * 1024;
    const int key = (lr >> 1) & 3;

    for (int k0 = 0; k0 < K; k0 += 64) {
        __syncthreads();
        // sub-tile 0 (K k0..k0+31)
        async16(pAh, dAh);
        async16(pAh + ar, dAh + 512);
        async16(pAl, dAl);
        async16(pAl + ar, dAl + 512);
        async16(pBh, dBh);
        async16(pBh + br, dBh + 512);
        async16(pBl, dBl);
        async16(pBl + br, dBl + 512);
        // sub-tile 1 (K k0+32..k0+63)
        async16(pAh + 64, dAh + 4096);
        async16(pAh + ar + 64, dAh + 4096 + 512);
        async16(pAl + 64, dAl + 4096);
        async16(pAl + ar + 64, dAl + 4096 + 512);
        async16(pBh + 64, dBh + 4096);
        async16(pBh + br + 64, dBh + 4096 + 512);
        async16(pBl + 64, dBl + 4096);
        async16(pBl + br + 64, dBl + 4096 + 512);
        pAh += 128;
        pAl += 128;
        pBh += 128;
        pBl += 128;
        __syncthreads();

#pragma unroll
        for (int s = 0; s < 2; s++) {
            const int sb = s * 4096;
            half8 ah[4], al[4], bh[4], bl[4];
#pragma unroll
            for (int i = 0; i < 4; i++) {
                const int ro = sb + (wr + i * 16 + lr) * 32 + ((lq ^ key) * 8);
                ah[i] = *(const half8*)&Ash[ro];
                al[i] = *(const half8*)&Asl[ro];
            }
#pragma unroll
            for (int j = 0; j < 4; j++) {
                const int ro = sb + (wc + j * 16 + lr) * 32 + ((lq ^ key) * 8);
                bh[j] = *(const half8*)&Bsh[ro];
                bl[j] = *(const half8*)&Bsl[ro];
            }
#pragma unroll
            for (int i = 0; i < 4; i++)
#pragma unroll
                for (int j = 0; j < 4; j++) {
                    acc[i][j] = __builtin_amdgcn_mfma_f32_16x16x32_f16(
                        ah[i], bl[j], acc[i][j], 0, 0, 0);
                    acc[i][j] = __builtin_amdgcn_mfma_f32_16x16x32_f16(
                        al[i], bh[j], acc[i][j], 0, 0, 0);
                    acc[i][j] = __builtin_amdgcn_mfma_f32_16x16x32_f16(
                        ah[i], bh[j], acc[i][j], 0, 0, 0);
                }
        }
    }
    float* Co = Cf + (size_t)blockIdx.z * splitStride;
#pragma unroll
    for (int i = 0; i < 4; i++) {
        const int m0 = bm + wr + i * 16 + lq * 4;
#pragma unroll
        for (int j = 0; j < 4; j++) {
            const int n = bn + wc + j * 16 + lr;
#pragma unroll
            for (int r = 0; r < 4; r++)
                Co[(size_t)(m0 + r) * ldc + n] = acc[i][j][r];
        }
    }
}

// ---------------------------------------------------------------------------
// fp16 GEMM: C[m][n] = sum_k A[m][k]*B[n][k] (+bias). A,B fp16 k-contig.
// BIAS_MODE: 0 none, 2 bias[m]. OUT_MODE: 0 f32->Cf(+z*splitStride),
// 2 fp16 dual rows (v at m, v*v at m+512). CONV: B = pad4T[py][px][ci].
// K mult of 64 (BK=64, two sub-tiles per barrier pair).
// ---------------------------------------------------------------------------
template <int BIAS_MODE, int OUT_MODE, bool CONV>
__global__ __launch_bounds__(256, 2) void mgemm16(
    const _Float16* __restrict__ A, const _Float16* __restrict__ B,
    const float* __restrict__ bias, float* __restrict__ Cf,
    _Float16* __restrict__ Ch, int K, int lda, int ldb, int ldc,
    size_t splitStride) {
    __shared__ _Float16 As[8192];
    __shared__ _Float16 Bs[8192];
    const int t = threadIdx.x, wave = t >> 6, lane = t & 63;
    const int bm = blockIdx.y * 128, bn = blockIdx.x * 128;
    const int kbase = blockIdx.z * K;
    const int wr = (wave >> 1) * 64, wc = (wave & 1) * 64;
    const int lq = lane >> 4, lr = lane & 15;
    const int srow = wave * 32 + (lane >> 2);
    const int scolg = (lane & 3) ^ ((lane >> 3) & 3);

    desync_sleep();

    f32x4 acc[4][4] = {};

    const char* Ap = (const char*)A +
                     ((size_t)(bm + srow) * lda + kbase) * 2 + scolg * 16;
    const char* Bp = (const char*)B +
                     ((size_t)(bn + srow) * ldb + kbase) * 2 + scolg * 16;
    const size_t Astep = (size_t)16 * lda * 2;
    const size_t Bstep = (size_t)16 * ldb * 2;
    _Float16* As0 = As + wave * 1024;
    _Float16* Bs0 = Bs + wave * 1024;
    const int key = (lr >> 1) & 3;

    for (int k0 = 0; k0 < K; k0 += 64) {
        __syncthreads();
        async16(Ap, As0);
        async16(Ap + Astep, As0 + 512);
        async16(Ap + 64, As0 + 4096);
        async16(Ap + Astep + 64, As0 + 4096 + 512);
        if (CONV) {
            const int kg = kbase + k0;
            const int rI = kg >> 9;
            const int dy = rI / 3, dx = rI - 3 * dy;
            const int ci0 = kg & 511;  // mult of 64; ci0+64 <= 512, same rI
            const int py = (bn >> 7) + dy;
            const int px = srow + dx;
            const char* Bc = (const char*)B +
                             (((size_t)py * 130 + px) * 512 + ci0) * 2 +
                             scolg * 16;
            async16(Bc, Bs0);
            async16(Bc + (size_t)16 * 512 * 2, Bs0 + 512);
            async16(Bc + 64, Bs0 + 4096);
            async16(Bc + (size_t)16 * 512 * 2 + 64, Bs0 + 4096 + 512);
        } else {
            async16(Bp, Bs0);
            async16(Bp + Bstep, Bs0 + 512);
            async16(Bp + 64, Bs0 + 4096);
            async16(Bp + Bstep + 64, Bs0 + 4096 + 512);
            Bp += 128;
        }
        Ap += 128;
        __syncthreads();

#pragma unroll
        for (int s = 0; s < 2; s++) {
            const int sb = s * 4096;
            half8 af[4], bf[4];
#pragma unroll
            for (int i = 0; i < 4; i++)
                af[i] = *(const half8*)&As[sb + (wr + i * 16 + lr) * 32 +
                                           (lq ^ key) * 8];
#pragma unroll
            for (int j = 0; j < 4; j++)
                bf[j] = *(const half8*)&Bs[sb + (wc + j * 16 + lr) * 32 +
                                           (lq ^ key) * 8];
#pragma unroll
            for (int i = 0; i < 4; i++)
#pragma unroll
                for (int j = 0; j < 4; j++)
                    acc[i][j] = __builtin_amdgcn_mfma_f32_16x16x32_f16(
                        af[i], bf[j], acc[i][j], 0, 0, 0);
        }
    }

    float* Co = (OUT_MODE == 0) ? Cf + (size_t)blockIdx.z * splitStride : nullptr;
#pragma unroll
    for (int i = 0; i < 4; i++) {
        const int m0 = bm + wr + i * 16 + lq * 4;
#pragma unroll
        for (int j = 0; j < 4; j++) {
            const int n = bn + wc + j * 16 + lr;
#pragma unroll
            for (int r = 0; r < 4; r++) {
                const int m = m0 + r;
                float v = acc[i][j][r];
                if (BIAS_MODE == 2) v += bias[m];
                if (OUT_MODE == 0) {
                    Co[(size_t)m * ldc + n] = v;
                } else {
                    Ch[(size_t)m * ldc + n] = (_Float16)v;
                    Ch[(size_t)(m + 512) * ldc + n] = (_Float16)(v * v);
                }
            }
        }
    }
}

// ---------------------------------------------------------------------------
// combine z-partials -> hi/lo fp16 pair. count multiple of 256.
__global__ __launch_bounds__(256) void combine_hilo(
    const float* __restrict__ part, _Float16* __restrict__ hi,
    _Float16* __restrict__ lo, int nz, size_t zs) {
    size_t i = (size_t)blockIdx.x * 256 + threadIdx.x;
    float s = 0.f;
    for (int z = 0; z < nz; z++) s += part[z * zs + i];
    _Float16 h = (_Float16)s;
    hi[i] = h;
    lo[i] = (_Float16)(s - (float)h);
}

// ---------------------------------------------------------------------------
// transpose f32 -> hi/lo fp16 pair: dsthi/lo[n][c] from src[c][n], zero-fill
// outside (cvalid, nvalid). grid (Npad/32, Cpad/32).
__global__ __launch_bounds__(256) void transpose_hilo(
    const float* __restrict__ src, _Float16* __restrict__ dsthi,
    _Float16* __restrict__ dstlo, long srcld, int dstld, int nvalid,
    int cvalid) {
    __shared__ float tile[32][33];
    const int t = threadIdx.x, tx = t & 31, ty = t >> 5;
    const int n0 = blockIdx.x * 32, c0 = blockIdx.y * 32;
    const int n = n0 + tx;
#pragma unroll
    for (int i = 0; i < 4; i++) {
        int c = c0 + ty + i * 8;
        tile[ty + i * 8][tx] =
            (c < cvalid && n < nvalid) ? src[(size_t)c * srcld + n] : 0.f;
    }
    __syncthreads();
#pragma unroll
    for (int i = 0; i < 4; i++) {
        int nn = ty + i * 8;
        float v = tile[tx][nn];
        _Float16 h = (_Float16)v;
        size_t o = (size_t)(n0 + nn) * dstld + c0 + tx;
        dsthi[o] = h;
        dstlo[o] = (_Float16)(v - (float)h);
    }
}

// transpose f32->fp16 (full-valid). src [C][srcld], dst fp16 [N][dstld].
__global__ __launch_bounds__(256) void transpose_cvt16(
    const float* __restrict__ src, _Float16* __restrict__ dst, long srcld,
    int dstld) {
    __shared__ float tile[32][33];
    const int t = threadIdx.x, tx = t & 31, ty = t >> 5;
    const int n0 = blockIdx.x * 32, c0 = blockIdx.y * 32;
#pragma unroll
    for (int i = 0; i < 4; i++)
        tile[ty + i * 8][tx] = src[(size_t)(c0 + ty + i * 8) * srcld + n0 + tx];
    __syncthreads();
#pragma unroll
    for (int i = 0; i < 4; i++) {
        int nn = ty + i * 8;
        dst[(size_t)(n0 + nn) * dstld + c0 + tx] = (_Float16)tile[tx][nn];
    }
}

// elementwise f32 -> fp16
__global__ __launch_bounds__(256) void cvt16(const float* __restrict__ src,
                                             _Float16* __restrict__ dst) {
    int i = blockIdx.x * 256 + threadIdx.x;
    dst[i] = (_Float16)src[i];
}

// conv weight permute: [o][ci][3][3] f32 -> [o][(dy*3+dx)*512+ci] fp16
__global__ __launch_bounds__(256) void convw_perm(const float* __restrict__ src,
                                                  _Float16* __restrict__ dst) {
    int idx = blockIdx.x * 256 + threadIdx.x;
    int o = idx / 4608, rem = idx - o * 4608;
    int r = rem >> 9, ci = rem & 511;
    dst[idx] = (_Float16)src[(size_t)o * 4608 + ci * 9 + r];
}

// out[n] = (addc ? addc[0] : 0) + sum_c vec[c] * mat[c*ldm + n]
__global__ __launch_bounds__(256) void fold_vec(
    const float* __restrict__ mat, const float* __restrict__ vec,
    const float* __restrict__ addc, float* __restrict__ outv, int C, int Nout,
    long ldm) {
    __shared__ float red[4][64];
    const int t = threadIdx.x, lane = t & 63, seg = t >> 6;
    const int n = blockIdx.x * 64 + lane;
    const int chunk = (C + 3) >> 2;
    const int start = seg * chunk;
    const int end = min(C, start + chunk);
    float s0 = 0.f, s1 = 0.f, s2 = 0.f, s3 = 0.f;
    if (n < Nout) {
        int c = start;
        for (; c + 3 < end; c += 4) {
            s0 = fmaf(vec[c], mat[(size_t)c * ldm + n], s0);
            s1 = fmaf(vec[c + 1], mat[(size_t)(c + 1) * ldm + n], s1);
            s2 = fmaf(vec[c + 2], mat[(size_t)(c + 2) * ldm + n], s2);
            s3 = fmaf(vec[c + 3], mat[(size_t)(c + 3) * ldm + n], s3);
        }
        for (; c < end; c++) s0 = fmaf(vec[c], mat[(size_t)c * ldm + n], s0);
    }
    red[seg][lane] = (s0 + s1) + (s2 + s3);
    __syncthreads();
    if (seg == 0 && n < Nout)
        outv[n] = red[0][lane] + red[1][lane] + red[2][lane] + red[3][lane] +
                  (addc ? addc[0] : 0.f);
}

// out[0] = dot(a, b) over C. One block.
__global__ __launch_bounds__(256) void dotbb(const float* __restrict__ a,
                                             const float* __restrict__ b,
                                             float* __restrict__ out, int C) {
    __shared__ float red[4];
    const int t = threadIdx.x;
    float s = 0.f;
    for (int c = t; c < C; c += 256) s = fmaf(a[c], b[c], s);
    s = wave_sum64(s);
    if ((t & 63) == 0) red[t >> 6] = s;
    __syncthreads();
    if (t == 0) out[0] = red[0] + red[1] + red[2] + red[3];
}

// Softmax: sums NZ logit planes (zs float stride) + rr, row in registers,
// single exp pass, fp16 out. cols = NPER*256.
template <int NPER, int NZ>
__global__ __launch_bounds__(256) void softmax2(const float* __restrict__ L,
                                                const float* __restrict__ rr,
                                                _Float16* __restrict__ S,
                                                size_t zs) {
    constexpr int NV = NPER / 4;
    __shared__ float redm[4], reds[4];
    const int t = threadIdx.x;
    const float* p = L + (size_t)blockIdx.x * (NPER * 256);
    _Float16* q = S + (size_t)blockIdx.x * (NPER * 256);
    f32x4 v[NV];
    float m = -3.0e38f;
#pragma unroll
    for (int i = 0; i < NV; i++) {
        const int c = t * 4 + i * 1024;
        f32x4 x = *(const f32x4*)(p + c);
        if (NZ == 2) x = x + *(const f32x4*)(p + zs + c);
        x = x + *(const f32x4*)(rr + c);
        v[i] = x;
        m = fmaxf(m, fmaxf(fmaxf(x[0], x[1]), fmaxf(x[2], x[3])));
    }
#pragma unroll
    for (int o = 32; o > 0; o >>= 1) m = fmaxf(m, __shfl_xor(m, o, 64));
    if ((t & 63) == 0) redm[t >> 6] = m;
    __syncthreads();
    m = fmaxf(fmaxf(redm[0], redm[1]), fmaxf(redm[2], redm[3]));
    float s = 0.f;
#pragma unroll
    for (int i = 0; i < NV; i++) {
        f32x4 x = v[i];
#pragma unroll
        for (int j = 0; j < 4; j++) {
            x[j] = __expf(x[j] - m);
            s += x[j];
        }
        v[i] = x;
    }
    s = wave_sum64(s);
    if ((t & 63) == 0) reds[t >> 6] = s;
    __syncthreads();
    const float inv = 1.f / (reds[0] + reds[1] + reds[2] + reds[3]);
#pragma unroll
    for (int i = 0; i < NV; i++) {
        const int c = t * 4 + i * 1024;
        half4 h;
#pragma unroll
        for (int j = 0; j < 4; j++) h[j] = (_Float16)(v[i][j] * inv);
        *(half4*)(q + c) = h;
    }
}

// Per-channel mean & unbiased std (+1e-6). One block per channel.
__global__ __launch_bounds__(256) void chanstats_kernel(
    const float* __restrict__ x, float* __restrict__ cm,
    float* __restrict__ cstd, int N) {
    __shared__ float rs[4], rs2[4];
    const int t = threadIdx.x;
    const float* p = x + (size_t)blockIdx.x * N;
    float s = 0.f, s2 = 0.f;
    for (int i = t; i < N; i += 256) {
        float v = p[i];
        s += v;
        s2 = fmaf(v, v, s2);
    }
    s = wave_sum64(s);
    s2 = wave_sum64(s2);
    if ((t & 63) == 0) {
        rs[t >> 6] = s;
        rs2[t >> 6] = s2;
    }
    __syncthreads();
    if (t == 0) {
        float S = rs[0] + rs[1] + rs[2] + rs[3];
        float S2 = rs2[0] + rs2[1] + rs2[2] + rs2[3];
        float mean = S / N;
        float var = fmaxf((S2 - S * mean) / (N - 1), 0.f);
        cm[blockIdx.x] = mean;
        cstd[blockIdx.x] = sqrtf(var) + 1e-6f;
    }
}

// a5T[n][c] fp16 = std*instnorm(content5) + mean; pv = 2 z-planes [4096][1024]
__global__ __launch_bounds__(256) void epilogue5(
    const float* __restrict__ pv, const float* __restrict__ content,
    const float* __restrict__ cm, const float* __restrict__ cstd,
    _Float16* __restrict__ a5t) {
    int idx = blockIdx.x * 256 + threadIdx.x;  // n*512 + c
    int n = idx >> 9, c = idx & 511;
    const size_t SS = (size_t)4096 * 1024;
    float mean = pv[(size_t)n * 1024 + c] + pv[SS + (size_t)n * 1024 + c];
    float ex2 =
        pv[(size_t)n * 1024 + 512 + c] + pv[SS + (size_t)n * 1024 + 512 + c];
    float sd = sqrtf(fmaxf(ex2 - mean * mean, 0.f));
    float cn = (content[(size_t)c * 4096 + n] - cm[c]) / cstd[c];
    a5t[idx] = (_Float16)(fmaf(sd, cn, mean));
}

// pad4T interior <- a4 + upsample2(a5), one 1024-pixel chunk, 8 K-splits.
__global__ __launch_bounds__(256) void epilogue4(
    const float* __restrict__ part, const float* __restrict__ content,
    const float* __restrict__ cm, const float* __restrict__ cstd,
    const _Float16* __restrict__ a5t, _Float16* __restrict__ pad4t, int n0) {
    int idx = blockIdx.x * 256 + threadIdx.x;  // r*512 + c
    int r = idx >> 9, c = idx & 511;
    int n = n0 + r;
    const size_t SS = (size_t)1024 * 1024;
    float mean = 0.f, ex2 = 0.f;
#pragma unroll
    for (int z = 0; z < 8; z++) {
        mean += part[z * SS + (size_t)r * 1024 + c];
        ex2 += part[z * SS + (size_t)r * 1024 + 512 + c];
    }
    float sd = sqrtf(fmaxf(ex2 - mean * mean, 0.f));
    float cn = (content[(size_t)c * 16384 + n] - cm[c]) / cstd[c];
    int y = n >> 7, x = n & 127;
    float up = (float)a5t[(size_t)((y >> 1) * 64 + (x >> 1)) * 512 + c];
    pad4t[(size_t)((y + 1) * 130 + (x + 1)) * 512 + c] =
        (_Float16)(fmaf(sd, cn, mean) + up);
}

__global__ __launch_bounds__(256) void border_kernel(_Float16* __restrict__ pad) {
    int idx = blockIdx.x * 256 + threadIdx.x;  // pos*512 + c
    int pos = idx >> 9, c = idx & 511;
    int py, px;
    if (pos < 130) { py = 0; px = pos; }
    else if (pos < 260) { py = 129; px = pos - 130; }
    else if (pos < 388) { py = pos - 260 + 1; px = 0; }
    else { py = pos - 388 + 1; px = 129; }
    int sy = py == 0 ? 2 : (py == 129 ? 127 : py);
    int sx = px == 0 ? 2 : (px == 129 ? 127 : px);
    pad[(size_t)(py * 130 + px) * 512 + c] =
        pad[(size_t)(sy * 130 + sx) * 512 + c];
}

// ---------------------------------------------------------------------------

extern "C" void kernel_launch(void* const* d_in, const int* in_sizes, int n_in,
                              void* d_out, int out_size, void* d_ws,
                              size_t ws_size, hipStream_t stream) {
    (void)in_sizes; (void)n_in; (void)out_size; (void)ws_size;
    const float* content4 = (const float*)d_in[0];
    const float* style4 = (const float*)d_in[1];
    const float* content5 = (const float*)d_in[2];
    const float* style5 = (const float*)d_in[3];
    const float* ckey4 = (const float*)d_in[4];
    const float* skey4 = (const float*)d_in[5];
    const float* ckey5 = (const float*)d_in[6];
    const float* skey5 = (const float*)d_in[7];
    const float* f4w = (const float*)d_in[8];
    const float* f4b = (const float*)d_in[9];
    const float* g4w = (const float*)d_in[10];
    const float* g4b = (const float*)d_in[11];
    const float* h4w = (const float*)d_in[12];
    const float* h4b = (const float*)d_in[13];
    const float* f5w = (const float*)d_in[14];
    const float* f5b = (const float*)d_in[15];
    const float* g5w = (const float*)d_in[16];
    const float* g5b = (const float*)d_in[17];
    const float* h5w = (const float*)d_in[18];
    const float* h5b = (const float*)d_in[19];
    const float* convw = (const float*)d_in[20];
    const float* convb = (const float*)d_in[21];
    float* out = (float*)d_out;
    char* ws = (char*)d_ws;

    // ---- persistent regions (byte offsets) ----
    _Float16* PAD4T = (_Float16*)(ws + 0);         // [130][130][512]
    _Float16* A5T = (_Float16*)(ws + 17305600);    // [4096][512]
    float* STATS = (float*)(ws + 21499904);        // 2048 f32
    _Float16* H4W = (_Float16*)(ws + 21508096);    // [512][512]
    _Float16* H5W = (_Float16*)(ws + 22032384);
    _Float16* CONVW = (_Float16*)(ws + 22556672);  // [512][4608]
    float* U5 = (float*)(ws + 27275264);           // 1472
    float* R5 = (float*)(ws + 27283456);           // 1024
    float* U4 = (float*)(ws + 27291648);           // 960
    float* R4 = (float*)(ws + 27299840);           // 4096
    float* BB5 = (float*)(ws + 27316224);
    float* BB4 = (float*)(ws + 27316480);
    char* A0 = ws + 27320320;  // arena

    float* cm4 = STATS, *cstd4 = STATS + 512, *cm5 = STATS + 1024,
         *cstd5 = STATS + 1536;

    chanstats_kernel<<<512, 256, 0, stream>>>(content5, cm5, cstd5, 4096);
    chanstats_kernel<<<512, 256, 0, stream>>>(content4, cm4, cstd4, 16384);
    cvt16<<<1024, 256, 0, stream>>>(h4w, H4W);
    cvt16<<<1024, 256, 0, stream>>>(h5w, H5W);
    convw_perm<<<9216, 256, 0, stream>>>(convw, CONVW);

    // ================= Layer 5 (Nc=4096, Ns=1024, Ck=1472->1536) ===========
    {
        _Float16* STT5 = (_Float16*)(A0 + 0);         // [1024][512]
        _Float16* HCAT5 = (_Float16*)(A0 + 1048576);  // [1024][1024]
        _Float16* T5h = (_Float16*)(A0 + 3145728);    // [1024][1536]
        _Float16* T5l = (_Float16*)(A0 + 6291456);
        _Float16* FWh = (_Float16*)(A0 + 9437184);    // [1536][1536]
        _Float16* FWl = (_Float16*)(A0 + 14155776);
        _Float16* GWh = (_Float16*)(A0 + 18874368);
        _Float16* GWl = (_Float16*)(A0 + 23592960);
        float* PM5 = (float*)(A0 + 28311552);         // 3x[1536][1536] f32
        _Float16* M5h = (_Float16*)(A0 + 56623104);   // [1536][1536]
        _Float16* M5l = (_Float16*)(A0 + 61341696);
        _Float16* SKh = (_Float16*)(A0 + 9437184);    // [1024][1536] (post-PM5)
        _Float16* SKl = (_Float16*)(A0 + 12582912);
        float* PT5 = (float*)(A0 + 15728640);         // 3x[1024][1536] f32
        _Float16* CKh = (_Float16*)(A0 + 9437184);    // [4096][1536] (post-T5)
        _Float16* CKl = (_Float16*)(A0 + 22020096);
        float* LOG5 = (float*)(A0 + 34603008);        // 2x[4096][1024] f32
        _Float16* S5 = (_Float16*)(A0 + 9437184);     // [4096][1024] (post-log)

        dotbb<<<1, 256, 0, stream>>>(f5b, g5b, BB5, 1472);
        fold_vec<<<23, 256, 0, stream>>>(g5w, f5b, nullptr, U5, 1472, 1472, 1472);
        fold_vec<<<16, 256, 0, stream>>>(skey5, U5, BB5, R5, 1472, 1024, 1024);

        transpose_hilo<<<dim3(48, 48), 256, 0, stream>>>(f5w, FWh, FWl, 1472,
                                                         1536, 1472, 1472);
        transpose_hilo<<<dim3(48, 48), 256, 0, stream>>>(g5w, GWh, GWl, 1472,
                                                         1536, 1472, 1472);
        // M5 = FW x GW, K=1536 split z=3
        mgemm_hl<<<dim3(12, 12, 3), 256, 0, stream>>>(
            FWh, FWl, GWh, GWl, PM5, 512, 1536, 1536, 1536,
            (size_t)1536 * 1536);
        combine_hilo<<<9216, 256, 0, stream>>>(PM5, M5h, M5l, 3,
                                               (size_t)1536 * 1536);
        transpose_hilo<<<dim3(32, 48), 256, 0, stream>>>(skey5, SKh, SKl, 1024,
                                                         1536, 1024, 1472);
        // T5 = SK x M5, K=1536 split z=3
        mgemm_hl<<<dim3(12, 8, 3), 256, 0, stream>>>(
            SKh, SKl, M5h, M5l, PT5, 512, 1536, 1536, 1536,
            (size_t)1024 * 1536);
        combine_hilo<<<6144, 256, 0, stream>>>(PT5, T5h, T5l, 3,
                                               (size_t)1024 * 1536);
        transpose_cvt16<<<dim3(32, 16), 256, 0, stream>>>(style5, STT5, 1024, 512);
        mgemm16<2, 2, false><<<dim3(8, 4), 256, 0, stream>>>(
            H5W, STT5, h5b, nullptr, HCAT5, 512, 512, 512, 1024, 0);
        transpose_hilo<<<dim3(128, 48), 256, 0, stream>>>(ckey5, CKh, CKl, 4096,
                                                          1536, 4096, 1472);
        // logits = CK x T5, K=1536 split z=2 -> 2 planes
        mgemm_hl<<<dim3(8, 32, 2), 256, 0, stream>>>(
            CKh, CKl, T5h, T5l, LOG5, 768, 1536, 1536, 1024,
            (size_t)4096 * 1024);
        softmax2<4, 2><<<4096, 256, 0, stream>>>(LOG5, R5, S5,
                                                 (size_t)4096 * 1024);
        // PV, K=1024 split z=2 -> 2 planes into LOG5 region
        mgemm16<0, 0, false><<<dim3(8, 32, 2), 256, 0, stream>>>(
            S5, HCAT5, nullptr, LOG5, nullptr, 512, 1024, 1024, 1024,
            (size_t)4096 * 1024);
        epilogue5<<<8192, 256, 0, stream>>>(LOG5, content5, cm5, cstd5, A5T);
    }

    // ================= Layer 4 (Nc=16384, Ns=4096, Ck=960->1024) ===========
    {
        _Float16* T4h = (_Float16*)(A0 + 0);          // [4096][1024]
        _Float16* T4l = (_Float16*)(A0 + 8388608);
        _Float16* M4h = (_Float16*)(A0 + 16777216);   // [1024][1024]
        _Float16* M4l = (_Float16*)(A0 + 18874368);
        _Float16* FWh = (_Float16*)(A0 + 20971520);   // [1024][1024]
        _Float16* FWl = (_Float16*)(A0 + 23068672);
        _Float16* GWh = (_Float16*)(A0 + 25165824);
        _Float16* GWl = (_Float16*)(A0 + 27262976);
        float* PM4 = (float*)(A0 + 29360128);         // 4x[1024][1024] f32
        _Float16* SKh = (_Float16*)(A0 + 20971520);   // [4096][1024] (post-PM4)
        _Float16* SKl = (_Float16*)(A0 + 29360128);
        float* PT4 = (float*)(A0 + 37748736);         // 2x[4096][1024] f32
        _Float16* HCAT4 = (_Float16*)(A0 + 16777216); // [1024][4096] (post-T4)
        _Float16* STT4 = (_Float16*)(A0 + 25165824);  // [4096][512]
        _Float16* CKh = (_Float16*)(A0 + 29360128);   // [1024][1024] per chunk
        _Float16* CKl = (_Float16*)(A0 + 31457280);
        _Float16* S4 = (_Float16*)(A0 + 25165824);    // [1024][4096] (in loop)
        float* LOGR = (float*)(A0 + 33554432);        // 2x[1024][4096] f32/PART

        dotbb<<<1, 256, 0, stream>>>(f4b, g4b, BB4, 960);
        fold_vec<<<15, 256, 0, stream>>>(g4w, f4b, nullptr, U4, 960, 960, 960);
        fold_vec<<<64, 256, 0, stream>>>(skey4, U4, BB4, R4, 960, 4096, 4096);

        transpose_hilo<<<dim3(32, 32), 256, 0, stream>>>(f4w, FWh, FWl, 960,
                                                         1024, 960, 960);
        transpose_hilo<<<dim3(32, 32), 256, 0, stream>>>(g4w, GWh, GWl, 960,
                                                         1024, 960, 960);
        // M4 = FW x GW, K=1024 split z=4
        mgemm_hl<<<dim3(8, 8, 4), 256, 0, stream>>>(
            FWh, FWl, GWh, GWl, PM4, 256, 1024, 1024, 1024,
            (size_t)1024 * 1024);
        combine_hilo<<<4096, 256, 0, stream>>>(PM4, M4h, M4l, 4,
                                               (size_t)1024 * 1024);
        transpose_hilo<<<dim3(128, 32), 256, 0, stream>>>(skey4, SKh, SKl, 4096,
                                                          1024, 4096, 960);
        // T4 = SK x M4, K=1024 split z=2
        mgemm_hl<<<dim3(8, 32, 2), 256, 0, stream>>>(
            SKh, SKl, M4h, M4l, PT4, 512, 1024, 1024, 1024,
            (size_t)4096 * 1024);
        combine_hilo<<<16384, 256, 0, stream>>>(PT4, T4h, T4l, 2,
                                                (size_t)4096 * 1024);
        transpose_cvt16<<<dim3(128, 16), 256, 0, stream>>>(style4, STT4, 4096, 512);
        mgemm16<2, 2, false><<<dim3(32, 4), 256, 0, stream>>>(
            H4W, STT4, h4b, nullptr, HCAT4, 512, 512, 512, 4096, 0);

        for (int chunk = 0; chunk < 16; chunk++) {
            const int n0 = chunk * 1024;
            transpose_hilo<<<dim3(32, 32), 256, 0, stream>>>(
                ckey4 + n0, CKh, CKl, 16384, 1024, 1024, 960);
            // logits = CK x T4, K=1024 split z=2 -> 2 planes
            mgemm_hl<<<dim3(32, 8, 2), 256, 0, stream>>>(
                CKh, CKl, T4h, T4l, LOGR, 512, 1024, 1024, 4096,
                (size_t)1024 * 4096);
            softmax2<16, 2><<<1024, 256, 0, stream>>>(LOGR, R4, S4,
                                                      (size_t)1024 * 4096);
            // PV, K=4096 split z=8 -> 8 planes into LOGR region
            mgemm16<0, 0, false><<<dim3(8, 8, 8), 256, 0, stream>>>(
                S4, HCAT4, nullptr, LOGR, nullptr, 512, 4096, 4096, 1024,
                (size_t)1024 * 1024);
            epilogue4<<<2048, 256, 0, stream>>>(LOGR, content4, cm4, cstd4, A5T,
                                                PAD4T, n0);
        }
    }

    border_kernel<<<1032, 256, 0, stream>>>(PAD4T);
    mgemm16<2, 0, true><<<dim3(128, 4), 256, 0, stream>>>(
        CONVW, PAD4T, convb, out, nullptr, 4608, 4608, 512, 16384, 0);
}